// Round 2
// baseline (1270.262 us; speedup 1.0000x reference)
//
#include <hip/hip_runtime.h>

#define D64 64
#define EPS 1e-16f

// ---- sortable-uint encoding for float atomicMax ----
__device__ __forceinline__ unsigned int enc_f(float f) {
    unsigned int u = __float_as_uint(f);
    return (u & 0x80000000u) ? ~u : (u | 0x80000000u);
}
__device__ __forceinline__ float dec_f(unsigned int u) {
    return (u & 0x80000000u) ? __uint_as_float(u & 0x7fffffffu)
                             : __uint_as_float(~u);
}

// ---- kernel 1: q,k,v,skip = x @ W + b ----
__global__ __launch_bounds__(256) void qkvs_kernel(
    const float* __restrict__ x,
    const float* __restrict__ Wq, const float* __restrict__ bq,
    const float* __restrict__ Wk, const float* __restrict__ bk,
    const float* __restrict__ Wv, const float* __restrict__ bv,
    const float* __restrict__ Ws, const float* __restrict__ bs,
    float* __restrict__ q, float* __restrict__ k, float* __restrict__ v,
    float* __restrict__ skip, int n_nodes)
{
    __shared__ float wq[4096], wk[4096], wv[4096];
    __shared__ float xs[16 * 64];
    __shared__ float bqs[64], bks[64], bvs[64], bss[64];
    int t = threadIdx.x;
    for (int i = t; i < 1024; i += 256) {
        ((float4*)wq)[i] = ((const float4*)Wq)[i];
        ((float4*)wk)[i] = ((const float4*)Wk)[i];
        ((float4*)wv)[i] = ((const float4*)Wv)[i];
    }
    if (t < 64) { bqs[t] = bq[t]; bks[t] = bk[t]; bvs[t] = bv[t]; bss[t] = bs[t]; }
    __syncthreads();

    int d  = t & 63;
    int j0 = t >> 6;           // wave id 0..3, each wave handles 4 nodes of the 16-tile
    int ntiles = (n_nodes + 15) / 16;
    for (int tile = blockIdx.x; tile < ntiles; tile += gridDim.x) {
        int base = tile * 16;
        __syncthreads();   // protect xs against previous-iter readers
        if (base + 16 <= n_nodes) {
            ((float4*)xs)[t] = ((const float4*)x)[(size_t)base * 16 + t];
        } else {
            for (int i = t; i < 1024; i += 256) {
                int node = base + (i >> 6);
                xs[i] = (node < n_nodes) ? x[(size_t)node * 64 + (i & 63)] : 0.0f;
            }
        }
        __syncthreads();

        float aq[4], ak[4], av[4], asv[4];
        #pragma unroll
        for (int j = 0; j < 4; ++j) { aq[j] = bqs[d]; ak[j] = bks[d]; av[j] = bvs[d]; asv[j] = bss[d]; }
        #pragma unroll 8
        for (int i = 0; i < 64; ++i) {
            float w0 = wq[i * 64 + d];
            float w1 = wk[i * 64 + d];
            float w2 = wv[i * 64 + d];
            float w3 = Ws[i * 64 + d];     // L1-resident (16 KB), coalesced
            #pragma unroll
            for (int j = 0; j < 4; ++j) {
                float xi = xs[(j0 * 4 + j) * 64 + i];   // wave-uniform broadcast
                aq[j]  += xi * w0;
                ak[j]  += xi * w1;
                av[j]  += xi * w2;
                asv[j] += xi * w3;
            }
        }
        #pragma unroll
        for (int j = 0; j < 4; ++j) {
            int node = base + j0 * 4 + j;
            if (node < n_nodes) {
                size_t o = (size_t)node * 64 + d;
                q[o] = aq[j]; k[o] = ak[j]; v[o] = av[j]; skip[o] = asv[j];
            }
        }
    }
}

// ---- kernel 2: per-edge logits + segment max ----
__global__ __launch_bounds__(256) void logits_kernel(
    const float* __restrict__ q, const float* __restrict__ k,
    const int* __restrict__ src, const int* __restrict__ dst,
    float* __restrict__ logits, unsigned int* __restrict__ mbuf, int E)
{
    int gid = blockIdx.x * 256 + threadIdx.x;
    int e = gid >> 4;
    int l = gid & 15;
    if (e >= E) return;
    int s = src[e], d = dst[e];
    float4 qi = ((const float4*)q)[(size_t)d * 16 + l];
    float4 kj = ((const float4*)k)[(size_t)s * 16 + l];
    float p = qi.x * kj.x + qi.y * kj.y + qi.z * kj.z + qi.w * kj.w;
    p += __shfl_xor(p, 1);
    p += __shfl_xor(p, 2);
    p += __shfl_xor(p, 4);
    p += __shfl_xor(p, 8);
    if (l == 0) {
        float logit = p * 0.125f;   // 1/sqrt(64)
        logits[e] = logit;
        atomicMax(mbuf + d, enc_f(logit));
    }
}

// ---- kernel 3: e = exp(logit - m[dst]); scatter e*v[src] into agg[dst] ----
__global__ __launch_bounds__(256) void scatter_kernel(
    const float* __restrict__ v, const float* __restrict__ logits,
    const unsigned int* __restrict__ mbuf,
    const int* __restrict__ src, const int* __restrict__ dst,
    float* __restrict__ agg, float* __restrict__ denom, int E)
{
    int gid = blockIdx.x * 256 + threadIdx.x;
    int e = gid >> 4;
    int l = gid & 15;
    if (e >= E) return;
    int s = src[e], d = dst[e];
    float m  = dec_f(mbuf[d]);
    float ev = expf(logits[e] - m);
    float4 v4 = ((const float4*)v)[(size_t)s * 16 + l];
    float* ag = agg + (size_t)d * 64 + l * 4;
    atomicAdd(ag + 0, ev * v4.x);
    atomicAdd(ag + 1, ev * v4.y);
    atomicAdd(ag + 2, ev * v4.z);
    atomicAdd(ag + 3, ev * v4.w);
    if (l == 0) atomicAdd(denom + d, ev);
}

// ---- kernel 4: out_node = relu(agg/(denom+eps) + skip); pool into graphs ----
__global__ __launch_bounds__(256) void finalize_kernel(
    const float* __restrict__ agg, const float* __restrict__ denom,
    const float* __restrict__ skip, const int* __restrict__ batch,
    float* __restrict__ out, float* __restrict__ cnt, int n_nodes)
{
    int idx = blockIdx.x * 256 + threadIdx.x;
    int node = idx >> 6;
    int d = idx & 63;
    if (node >= n_nodes) return;
    float val = agg[idx] / (denom[node] + EPS) + skip[idx];
    val = fmaxf(val, 0.0f);
    int g = batch[node];
    atomicAdd(out + (size_t)g * 64 + d, val);
    if (d == 0) atomicAdd(cnt + g, 1.0f);
}

// ---- kernel 5: divide pooled sums by counts ----
__global__ __launch_bounds__(256) void pool_div_kernel(
    float* __restrict__ out, const float* __restrict__ cnt, int n)
{
    int idx = blockIdx.x * 256 + threadIdx.x;
    if (idx >= n) return;
    int g = idx >> 6;
    out[idx] /= fmaxf(cnt[g], 1.0f);
}

extern "C" void kernel_launch(void* const* d_in, const int* in_sizes, int n_in,
                              void* d_out, int out_size, void* d_ws, size_t ws_size,
                              hipStream_t stream) {
    const float* x     = (const float*)d_in[0];
    const int*   eidx  = (const int*)d_in[1];
    const int*   batch = (const int*)d_in[2];
    const float* Wq = (const float*)d_in[3];
    const float* bq = (const float*)d_in[4];
    const float* Wk = (const float*)d_in[5];
    const float* bk = (const float*)d_in[6];
    const float* Wv = (const float*)d_in[7];
    const float* bv = (const float*)d_in[8];
    const float* Ws = (const float*)d_in[9];
    const float* bs = (const float*)d_in[10];

    int N = in_sizes[0] / D64;
    int E = in_sizes[1] / 2;
    const int* src = eidx;
    const int* dst = eidx + E;

    char* w = (char*)d_ws;
    size_t NB = (size_t)N * D64 * sizeof(float);   // 12.8 MB per [N,64] buffer
    float*        q      = (float*)(w);
    float*        k      = (float*)(w + NB);
    float*        v      = (float*)(w + 2 * NB);
    float*        skip   = (float*)(w + 3 * NB);
    float*        agg    = (float*)(w + 4 * NB);
    float*        logits = (float*)(w + 5 * NB);
    unsigned int* mbuf   = (unsigned int*)(w + 5 * NB + (size_t)E * 4);
    float*        denom  = (float*)(w + 5 * NB + (size_t)E * 4 + (size_t)N * 4);
    float*        cnt    = (float*)(w + 5 * NB + (size_t)E * 4 + 2 * (size_t)N * 4);

    // zero: agg + logits + mbuf + denom + cnt (contiguous region from agg)
    size_t zbytes = NB + (size_t)E * 4 + 2 * (size_t)N * 4 + 64 * sizeof(float);
    hipMemsetAsync(w + 4 * NB, 0, zbytes, stream);
    hipMemsetAsync(d_out, 0, (size_t)out_size * sizeof(float), stream);

    qkvs_kernel<<<512, 256, 0, stream>>>(x, Wq, bq, Wk, bk, Wv, bv, Ws, bs,
                                         q, k, v, skip, N);
    int blocks_e = (E * 16 + 255) / 256;
    logits_kernel<<<blocks_e, 256, 0, stream>>>(q, k, src, dst, logits, mbuf, E);
    scatter_kernel<<<blocks_e, 256, 0, stream>>>(v, logits, mbuf, src, dst, agg, denom, E);
    finalize_kernel<<<(N * 64 + 255) / 256, 256, 0, stream>>>(agg, denom, skip, batch,
                                                              (float*)d_out, cnt, N);
    pool_div_kernel<<<(out_size + 255) / 256, 256, 0, stream>>>((float*)d_out,
                                                                (const float*)cnt, out_size);
}

// Round 3
// 402.255 us; speedup vs baseline: 3.1579x; 3.1579x over previous
//
#include <hip/hip_runtime.h>

#define D64 64
#define EPS 1e-16f

// ---- kernel 1: q,k,v,skip = x @ W + b ----
__global__ __launch_bounds__(256) void qkvs_kernel(
    const float* __restrict__ x,
    const float* __restrict__ Wq, const float* __restrict__ bq,
    const float* __restrict__ Wk, const float* __restrict__ bk,
    const float* __restrict__ Wv, const float* __restrict__ bv,
    const float* __restrict__ Ws, const float* __restrict__ bs,
    float* __restrict__ q, float* __restrict__ k, float* __restrict__ v,
    float* __restrict__ skip, int n_nodes)
{
    __shared__ float wq[4096], wk[4096], wv[4096];
    __shared__ float xs[16 * 64];
    __shared__ float bqs[64], bks[64], bvs[64], bss[64];
    int t = threadIdx.x;
    for (int i = t; i < 1024; i += 256) {
        ((float4*)wq)[i] = ((const float4*)Wq)[i];
        ((float4*)wk)[i] = ((const float4*)Wk)[i];
        ((float4*)wv)[i] = ((const float4*)Wv)[i];
    }
    if (t < 64) { bqs[t] = bq[t]; bks[t] = bk[t]; bvs[t] = bv[t]; bss[t] = bs[t]; }
    __syncthreads();

    int d  = t & 63;
    int j0 = t >> 6;
    int ntiles = (n_nodes + 15) / 16;
    for (int tile = blockIdx.x; tile < ntiles; tile += gridDim.x) {
        int base = tile * 16;
        __syncthreads();
        if (base + 16 <= n_nodes) {
            ((float4*)xs)[t] = ((const float4*)x)[(size_t)base * 16 + t];
        } else {
            for (int i = t; i < 1024; i += 256) {
                int node = base + (i >> 6);
                xs[i] = (node < n_nodes) ? x[(size_t)node * 64 + (i & 63)] : 0.0f;
            }
        }
        __syncthreads();

        float aq[4], ak[4], av[4], asv[4];
        #pragma unroll
        for (int j = 0; j < 4; ++j) { aq[j] = bqs[d]; ak[j] = bks[d]; av[j] = bvs[d]; asv[j] = bss[d]; }
        #pragma unroll 8
        for (int i = 0; i < 64; ++i) {
            float w0 = wq[i * 64 + d];
            float w1 = wk[i * 64 + d];
            float w2 = wv[i * 64 + d];
            float w3 = Ws[i * 64 + d];
            #pragma unroll
            for (int j = 0; j < 4; ++j) {
                float xi = xs[(j0 * 4 + j) * 64 + i];
                aq[j]  += xi * w0;
                ak[j]  += xi * w1;
                av[j]  += xi * w2;
                asv[j] += xi * w3;
            }
        }
        #pragma unroll
        for (int j = 0; j < 4; ++j) {
            int node = base + j0 * 4 + j;
            if (node < n_nodes) {
                size_t o = (size_t)node * 64 + d;
                q[o] = aq[j]; k[o] = ak[j]; v[o] = av[j]; skip[o] = asv[j];
            }
        }
    }
}

// ---- kernel 2: in-degree histogram ----
__global__ __launch_bounds__(256) void hist_kernel(
    const int* __restrict__ dst, int* __restrict__ deg, int E)
{
    int e = blockIdx.x * 256 + threadIdx.x;
    if (e < E) atomicAdd(deg + dst[e], 1);
}

// ---- kernel 3: exclusive prefix sum over deg -> rowstart (single block) ----
__global__ __launch_bounds__(1024) void scan_kernel(
    const int* __restrict__ deg, int* __restrict__ rowstart, int N, int E)
{
    __shared__ int sums[1024];
    int t = threadIdx.x;
    int chunk = (N + 1023) >> 10;
    int beg = t * chunk;
    int end = min(beg + chunk, N);
    int s = 0;
    for (int i = beg; i < end; ++i) s += deg[i];
    sums[t] = s;
    __syncthreads();
    for (int off = 1; off < 1024; off <<= 1) {
        int add = (t >= off) ? sums[t - off] : 0;
        __syncthreads();
        sums[t] += add;
        __syncthreads();
    }
    int prefix = (t == 0) ? 0 : sums[t - 1];
    for (int i = beg; i < end; ++i) { rowstart[i] = prefix; prefix += deg[i]; }
    if (t == 0) rowstart[N] = E;
}

// ---- kernel 4: CSR fill — reorder src ids by dst ----
__global__ __launch_bounds__(256) void fill_kernel(
    const int* __restrict__ src, const int* __restrict__ dst,
    const int* __restrict__ rowstart, int* __restrict__ cursor,
    int* __restrict__ srcs, int E)
{
    int e = blockIdx.x * 256 + threadIdx.x;
    if (e >= E) return;
    int d = dst[e];
    int pos = rowstart[d] + atomicAdd(cursor + d, 1);
    srcs[pos] = src[e];
}

// ---- kernel 5: fused attention gather + skip + relu + graph pool ----
// 16 lanes per dst node; online softmax in registers; no agg materialization.
__global__ __launch_bounds__(256) void attn_gather_kernel(
    const float* __restrict__ q, const float* __restrict__ k,
    const float* __restrict__ v, const float* __restrict__ skip,
    const int* __restrict__ rowstart, const int* __restrict__ srcs,
    const int* __restrict__ batch,
    float* __restrict__ out, float* __restrict__ cnt, int N)
{
    int t = threadIdx.x;
    int l = t & 15;
    int node = (blockIdx.x * 256 + t) >> 4;
    bool valid = node < N;

    float4 qv = make_float4(0.f, 0.f, 0.f, 0.f);
    int p0 = 0, p1 = 0;
    if (valid) {
        qv = ((const float4*)q)[(size_t)node * 16 + l];
        p0 = rowstart[node];
        p1 = rowstart[node + 1];
    }

    float4 acc = make_float4(0.f, 0.f, 0.f, 0.f);
    float den = 0.f;
    float m = -INFINITY;

    for (int p = p0; p < p1; ++p) {
        int s = srcs[p];                                   // uniform across 16-lane group
        float4 kj = ((const float4*)k)[(size_t)s * 16 + l];
        float dp = qv.x * kj.x + qv.y * kj.y + qv.z * kj.z + qv.w * kj.w;
        dp += __shfl_xor(dp, 1);
        dp += __shfl_xor(dp, 2);
        dp += __shfl_xor(dp, 4);
        dp += __shfl_xor(dp, 8);
        float logit = dp * 0.125f;                          // 1/sqrt(64)
        float4 vj = ((const float4*)v)[(size_t)s * 16 + l];
        if (logit > m) {                                    // online softmax rescale
            float sc = __expf(m - logit);                   // first iter: exp(-inf)=0
            den *= sc; acc.x *= sc; acc.y *= sc; acc.z *= sc; acc.w *= sc;
            m = logit;
        }
        float ev = __expf(logit - m);
        den += ev;
        acc.x += ev * vj.x; acc.y += ev * vj.y;
        acc.z += ev * vj.z; acc.w += ev * vj.w;
    }

    float4 val = make_float4(0.f, 0.f, 0.f, 0.f);
    int g = -1;
    if (valid) {
        float inv = 1.0f / (den + EPS);                     // den==0 -> acc==0 -> 0
        float4 sk = ((const float4*)skip)[(size_t)node * 16 + l];
        val.x = fmaxf(acc.x * inv + sk.x, 0.f);
        val.y = fmaxf(acc.y * inv + sk.y, 0.f);
        val.z = fmaxf(acc.z * inv + sk.z, 0.f);
        val.w = fmaxf(acc.w * inv + sk.w, 0.f);
        g = batch[node];
    }

    // wave-level pool: batch sorted => most waves have one graph for all 4 nodes
    int g0 = __shfl(g, 0);
    bool uni = __all(g == g0);
    if (uni) {
        if (g0 >= 0) {
            val.x += __shfl_xor(val.x, 16); val.x += __shfl_xor(val.x, 32);
            val.y += __shfl_xor(val.y, 16); val.y += __shfl_xor(val.y, 32);
            val.z += __shfl_xor(val.z, 16); val.z += __shfl_xor(val.z, 32);
            val.w += __shfl_xor(val.w, 16); val.w += __shfl_xor(val.w, 32);
            if ((t & 63) < 16) {
                float* o = out + (size_t)g0 * 64 + l * 4;
                atomicAdd(o + 0, val.x);
                atomicAdd(o + 1, val.y);
                atomicAdd(o + 2, val.z);
                atomicAdd(o + 3, val.w);
            }
            if ((t & 63) == 0) atomicAdd(cnt + g0, 4.0f);
        }
    } else if (valid) {
        float* o = out + (size_t)g * 64 + l * 4;
        atomicAdd(o + 0, val.x);
        atomicAdd(o + 1, val.y);
        atomicAdd(o + 2, val.z);
        atomicAdd(o + 3, val.w);
        if (l == 0) atomicAdd(cnt + g, 1.0f);
    }
}

// ---- kernel 6: divide pooled sums by counts ----
__global__ __launch_bounds__(256) void pool_div_kernel(
    float* __restrict__ out, const float* __restrict__ cnt, int n)
{
    int idx = blockIdx.x * 256 + threadIdx.x;
    if (idx >= n) return;
    int g = idx >> 6;
    out[idx] /= fmaxf(cnt[g], 1.0f);
}

extern "C" void kernel_launch(void* const* d_in, const int* in_sizes, int n_in,
                              void* d_out, int out_size, void* d_ws, size_t ws_size,
                              hipStream_t stream) {
    const float* x     = (const float*)d_in[0];
    const int*   eidx  = (const int*)d_in[1];
    const int*   batch = (const int*)d_in[2];
    const float* Wq = (const float*)d_in[3];
    const float* bq = (const float*)d_in[4];
    const float* Wk = (const float*)d_in[5];
    const float* bk = (const float*)d_in[6];
    const float* Wv = (const float*)d_in[7];
    const float* bv = (const float*)d_in[8];
    const float* Ws = (const float*)d_in[9];
    const float* bs = (const float*)d_in[10];

    int N = in_sizes[0] / D64;
    int E = in_sizes[1] / 2;
    const int* src = eidx;
    const int* dst = eidx + E;

    char* w = (char*)d_ws;
    size_t NB = (size_t)N * D64 * sizeof(float);   // 12.8 MB per [N,64] buffer
    float* q    = (float*)(w);
    float* k    = (float*)(w + NB);
    float* v    = (float*)(w + 2 * NB);
    float* skip = (float*)(w + 3 * NB);
    char*  p    = w + 4 * NB;
    int*   deg      = (int*)p;                 p += (size_t)N * 4;
    int*   cursor   = (int*)p;                 p += (size_t)N * 4;
    int*   rowstart = (int*)p;                 p += (size_t)(N + 1) * 4;
    int*   srcs     = (int*)p;                 p += (size_t)E * 4;
    float* cnt      = (float*)p;

    // zero deg+cursor (contiguous), cnt, d_out
    hipMemsetAsync(deg, 0, 2 * (size_t)N * 4, stream);
    hipMemsetAsync(cnt, 0, 64 * sizeof(float), stream);
    hipMemsetAsync(d_out, 0, (size_t)out_size * sizeof(float), stream);

    qkvs_kernel<<<512, 256, 0, stream>>>(x, Wq, bq, Wk, bk, Wv, bv, Ws, bs,
                                         q, k, v, skip, N);
    int blocks_e = (E + 255) / 256;
    hist_kernel<<<blocks_e, 256, 0, stream>>>(dst, deg, E);
    scan_kernel<<<1, 1024, 0, stream>>>(deg, rowstart, N, E);
    fill_kernel<<<blocks_e, 256, 0, stream>>>(src, dst, rowstart, cursor, srcs, E);
    int blocks_g = ((size_t)N * 16 + 255) / 256;
    attn_gather_kernel<<<blocks_g, 256, 0, stream>>>(q, k, v, skip, rowstart, srcs,
                                                     batch, (float*)d_out, cnt, N);
    pool_div_kernel<<<(out_size + 255) / 256, 256, 0, stream>>>((float*)d_out,
                                                                (const float*)cnt, out_size);
}

// Round 4
// 384.950 us; speedup vs baseline: 3.2998x; 1.0450x over previous
//
#include <hip/hip_runtime.h>

#define D64 64
#define EPS 1e-16f

__device__ __forceinline__ float dot4(float4 a, float4 b) {
    return a.x * b.x + a.y * b.y + a.z * b.z + a.w * b.w;
}
__device__ __forceinline__ float rsum16(float p) {
    p += __shfl_xor(p, 1);
    p += __shfl_xor(p, 2);
    p += __shfl_xor(p, 4);
    p += __shfl_xor(p, 8);
    return p;
}

// ---- kernel 1: q,k,v,skip = x @ W + b ; fused in-degree histogram ----
__global__ __launch_bounds__(256) void qkvs_kernel(
    const float* __restrict__ x,
    const float* __restrict__ Wq, const float* __restrict__ bq,
    const float* __restrict__ Wk, const float* __restrict__ bk,
    const float* __restrict__ Wv, const float* __restrict__ bv,
    const float* __restrict__ Ws, const float* __restrict__ bs,
    float* __restrict__ q, float* __restrict__ k, float* __restrict__ v,
    float* __restrict__ skip, int n_nodes,
    const int* __restrict__ dst, int* __restrict__ deg, int E)
{
    __shared__ float wq[4096], wk[4096], wv[4096];
    __shared__ float xs[16 * 64];
    __shared__ float bqs[64], bks[64], bvs[64], bss[64];
    int t = threadIdx.x;
    for (int i = t; i < 1024; i += 256) {
        ((float4*)wq)[i] = ((const float4*)Wq)[i];
        ((float4*)wk)[i] = ((const float4*)Wk)[i];
        ((float4*)wv)[i] = ((const float4*)Wv)[i];
    }
    if (t < 64) { bqs[t] = bq[t]; bks[t] = bk[t]; bvs[t] = bv[t]; bss[t] = bs[t]; }
    __syncthreads();

    int d  = t & 63;
    int j0 = t >> 6;
    int ntiles = (n_nodes + 15) / 16;
    for (int tile = blockIdx.x; tile < ntiles; tile += gridDim.x) {
        int base = tile * 16;
        __syncthreads();
        if (base + 16 <= n_nodes) {
            ((float4*)xs)[t] = ((const float4*)x)[(size_t)base * 16 + t];
        } else {
            for (int i = t; i < 1024; i += 256) {
                int node = base + (i >> 6);
                xs[i] = (node < n_nodes) ? x[(size_t)node * 64 + (i & 63)] : 0.0f;
            }
        }
        __syncthreads();

        float aq[4], ak[4], av[4], asv[4];
        #pragma unroll
        for (int j = 0; j < 4; ++j) { aq[j] = bqs[d]; ak[j] = bks[d]; av[j] = bvs[d]; asv[j] = bss[d]; }
        #pragma unroll 8
        for (int i = 0; i < 64; ++i) {
            float w0 = wq[i * 64 + d];
            float w1 = wk[i * 64 + d];
            float w2 = wv[i * 64 + d];
            float w3 = Ws[i * 64 + d];
            #pragma unroll
            for (int j = 0; j < 4; ++j) {
                float xi = xs[(j0 * 4 + j) * 64 + i];
                aq[j]  += xi * w0;
                ak[j]  += xi * w1;
                av[j]  += xi * w2;
                asv[j] += xi * w3;
            }
        }
        #pragma unroll
        for (int j = 0; j < 4; ++j) {
            int node = base + j0 * 4 + j;
            if (node < n_nodes) {
                size_t o = (size_t)node * 64 + d;
                q[o] = aq[j]; k[o] = ak[j]; v[o] = av[j]; skip[o] = asv[j];
            }
        }
    }

    // fused in-degree histogram (overlaps other blocks' GEMM work)
    for (int e = blockIdx.x * 256 + t; e < E; e += gridDim.x * 256)
        atomicAdd(deg + dst[e], 1);
}

// ---- kernel 2: exclusive prefix sum over deg -> rowstart (single block) ----
__global__ __launch_bounds__(1024) void scan_kernel(
    const int* __restrict__ deg, int* __restrict__ rowstart, int N, int E)
{
    __shared__ int sums[1024];
    int t = threadIdx.x;
    int chunk = (N + 1023) >> 10;
    int beg = t * chunk;
    int end = min(beg + chunk, N);
    int s = 0;
    for (int i = beg; i < end; ++i) s += deg[i];
    sums[t] = s;
    __syncthreads();
    for (int off = 1; off < 1024; off <<= 1) {
        int add = (t >= off) ? sums[t - off] : 0;
        __syncthreads();
        sums[t] += add;
        __syncthreads();
    }
    int prefix = (t == 0) ? 0 : sums[t - 1];
    for (int i = beg; i < end; ++i) { rowstart[i] = prefix; prefix += deg[i]; }
    if (t == 0) rowstart[N] = E;
}

// ---- kernel 3: CSR fill — reorder src ids by dst ----
__global__ __launch_bounds__(256) void fill_kernel(
    const int* __restrict__ src, const int* __restrict__ dst,
    const int* __restrict__ rowstart, int* __restrict__ cursor,
    int* __restrict__ srcs, int E)
{
    int e = blockIdx.x * 256 + threadIdx.x;
    if (e >= E) return;
    int d = dst[e];
    int pos = rowstart[d] + atomicAdd(cursor + d, 1);
    srcs[pos] = src[e];
}

// ---- kernel 4: fused attention gather + skip + relu + graph pool ----
// 16 lanes per dst node; 4-edge unrolled online softmax for memory-level parallelism.
__global__ __launch_bounds__(256) void attn_gather_kernel(
    const float* __restrict__ q, const float* __restrict__ k,
    const float* __restrict__ v, const float* __restrict__ skip,
    const int* __restrict__ rowstart, const int* __restrict__ srcs,
    const int* __restrict__ batch,
    float* __restrict__ out, float* __restrict__ cnt, int N)
{
    int t = threadIdx.x;
    int l = t & 15;
    int node = (blockIdx.x * 256 + t) >> 4;
    bool valid = node < N;

    float4 qv = make_float4(0.f, 0.f, 0.f, 0.f);
    int p0 = 0, p1 = 0;
    if (valid) {
        qv = ((const float4*)q)[(size_t)node * 16 + l];
        p0 = rowstart[node];
        p1 = rowstart[node + 1];
    }

    float4 acc = make_float4(0.f, 0.f, 0.f, 0.f);
    float den = 0.f;
    float m = -INFINITY;

    const float4* k4 = (const float4*)k;
    const float4* v4 = (const float4*)v;

    int p = p0;
    for (; p + 4 <= p1; p += 4) {
        // issue all independent loads first: 1 index cacheline + 8 gathers in flight
        int s0 = srcs[p + 0];
        int s1 = srcs[p + 1];
        int s2 = srcs[p + 2];
        int s3 = srcs[p + 3];
        float4 k0 = k4[(size_t)s0 * 16 + l];
        float4 k1 = k4[(size_t)s1 * 16 + l];
        float4 k2 = k4[(size_t)s2 * 16 + l];
        float4 k3 = k4[(size_t)s3 * 16 + l];
        float4 v0 = v4[(size_t)s0 * 16 + l];
        float4 v1 = v4[(size_t)s1 * 16 + l];
        float4 v2 = v4[(size_t)s2 * 16 + l];
        float4 v3 = v4[(size_t)s3 * 16 + l];

        float l0 = rsum16(dot4(qv, k0)) * 0.125f;
        float l1 = rsum16(dot4(qv, k1)) * 0.125f;
        float l2 = rsum16(dot4(qv, k2)) * 0.125f;
        float l3 = rsum16(dot4(qv, k3)) * 0.125f;

        float mx = fmaxf(fmaxf(l0, l1), fmaxf(l2, l3));
        if (mx > m) {
            float sc = __expf(m - mx);        // first quad: exp(-inf)=0
            den *= sc;
            acc.x *= sc; acc.y *= sc; acc.z *= sc; acc.w *= sc;
            m = mx;
        }
        float e0 = __expf(l0 - m);
        float e1 = __expf(l1 - m);
        float e2 = __expf(l2 - m);
        float e3 = __expf(l3 - m);
        den += (e0 + e1) + (e2 + e3);
        acc.x += e0 * v0.x + e1 * v1.x + e2 * v2.x + e3 * v3.x;
        acc.y += e0 * v0.y + e1 * v1.y + e2 * v2.y + e3 * v3.y;
        acc.z += e0 * v0.z + e1 * v1.z + e2 * v2.z + e3 * v3.z;
        acc.w += e0 * v0.w + e1 * v1.w + e2 * v2.w + e3 * v3.w;
    }
    for (; p < p1; ++p) {
        int s = srcs[p];
        float4 kj = k4[(size_t)s * 16 + l];
        float4 vj = v4[(size_t)s * 16 + l];
        float logit = rsum16(dot4(qv, kj)) * 0.125f;
        if (logit > m) {
            float sc = __expf(m - logit);
            den *= sc;
            acc.x *= sc; acc.y *= sc; acc.z *= sc; acc.w *= sc;
            m = logit;
        }
        float ev = __expf(logit - m);
        den += ev;
        acc.x += ev * vj.x; acc.y += ev * vj.y;
        acc.z += ev * vj.z; acc.w += ev * vj.w;
    }

    float4 val = make_float4(0.f, 0.f, 0.f, 0.f);
    int g = -1;
    if (valid) {
        float inv = 1.0f / (den + EPS);                 // den==0 -> acc==0 -> 0
        float4 sk = ((const float4*)skip)[(size_t)node * 16 + l];
        val.x = fmaxf(acc.x * inv + sk.x, 0.f);
        val.y = fmaxf(acc.y * inv + sk.y, 0.f);
        val.z = fmaxf(acc.z * inv + sk.z, 0.f);
        val.w = fmaxf(acc.w * inv + sk.w, 0.f);
        g = batch[node];
    }

    // wave-level pool: batch sorted => most waves have one graph for all 4 nodes
    int g0 = __shfl(g, 0);
    bool uni = __all(g == g0);
    if (uni) {
        if (g0 >= 0) {
            val.x += __shfl_xor(val.x, 16); val.x += __shfl_xor(val.x, 32);
            val.y += __shfl_xor(val.y, 16); val.y += __shfl_xor(val.y, 32);
            val.z += __shfl_xor(val.z, 16); val.z += __shfl_xor(val.z, 32);
            val.w += __shfl_xor(val.w, 16); val.w += __shfl_xor(val.w, 32);
            if ((t & 63) < 16) {
                float* o = out + (size_t)g0 * 64 + l * 4;
                atomicAdd(o + 0, val.x);
                atomicAdd(o + 1, val.y);
                atomicAdd(o + 2, val.z);
                atomicAdd(o + 3, val.w);
            }
            if ((t & 63) == 0) atomicAdd(cnt + g0, 4.0f);
        }
    } else if (valid) {
        float* o = out + (size_t)g * 64 + l * 4;
        atomicAdd(o + 0, val.x);
        atomicAdd(o + 1, val.y);
        atomicAdd(o + 2, val.z);
        atomicAdd(o + 3, val.w);
        if (l == 0) atomicAdd(cnt + g, 1.0f);
    }
}

// ---- kernel 5: divide pooled sums by counts ----
__global__ __launch_bounds__(256) void pool_div_kernel(
    float* __restrict__ out, const float* __restrict__ cnt, int n)
{
    int idx = blockIdx.x * 256 + threadIdx.x;
    if (idx >= n) return;
    int g = idx >> 6;
    out[idx] /= fmaxf(cnt[g], 1.0f);
}

extern "C" void kernel_launch(void* const* d_in, const int* in_sizes, int n_in,
                              void* d_out, int out_size, void* d_ws, size_t ws_size,
                              hipStream_t stream) {
    const float* x     = (const float*)d_in[0];
    const int*   eidx  = (const int*)d_in[1];
    const int*   batch = (const int*)d_in[2];
    const float* Wq = (const float*)d_in[3];
    const float* bq = (const float*)d_in[4];
    const float* Wk = (const float*)d_in[5];
    const float* bk = (const float*)d_in[6];
    const float* Wv = (const float*)d_in[7];
    const float* bv = (const float*)d_in[8];
    const float* Ws = (const float*)d_in[9];
    const float* bs = (const float*)d_in[10];

    int N = in_sizes[0] / D64;
    int E = in_sizes[1] / 2;
    const int* src = eidx;
    const int* dst = eidx + E;

    char* w = (char*)d_ws;
    size_t NB = (size_t)N * D64 * sizeof(float);   // 12.8 MB per [N,64] buffer
    float* q    = (float*)(w);
    float* k    = (float*)(w + NB);
    float* v    = (float*)(w + 2 * NB);
    float* skip = (float*)(w + 3 * NB);
    char*  p    = w + 4 * NB;
    int*   deg      = (int*)p;                 p += (size_t)N * 4;
    int*   cursor   = (int*)p;                 p += (size_t)N * 4;
    int*   rowstart = (int*)p;                 p += (size_t)(N + 1) * 4;
    int*   srcs     = (int*)p;                 p += (size_t)E * 4;
    float* cnt      = (float*)p;

    // zero deg+cursor (contiguous), cnt, d_out
    hipMemsetAsync(deg, 0, 2 * (size_t)N * 4, stream);
    hipMemsetAsync(cnt, 0, 64 * sizeof(float), stream);
    hipMemsetAsync(d_out, 0, (size_t)out_size * sizeof(float), stream);

    qkvs_kernel<<<1024, 256, 0, stream>>>(x, Wq, bq, Wk, bk, Wv, bv, Ws, bs,
                                          q, k, v, skip, N, dst, deg, E);
    scan_kernel<<<1, 1024, 0, stream>>>(deg, rowstart, N, E);
    int blocks_e = (E + 255) / 256;
    fill_kernel<<<blocks_e, 256, 0, stream>>>(src, dst, rowstart, cursor, srcs, E);
    int blocks_g = ((size_t)N * 16 + 255) / 256;
    attn_gather_kernel<<<blocks_g, 256, 0, stream>>>(q, k, v, skip, rowstart, srcs,
                                                     batch, (float*)d_out, cnt, N);
    pool_div_kernel<<<(out_size + 255) / 256, 256, 0, stream>>>((float*)d_out,
                                                                (const float*)cnt, out_size);
}